// Round 1
// 2255.983 us; speedup vs baseline: 1.0701x; 1.0701x over previous
//
#include <hip/hip_runtime.h>
#include <hip/hip_fp16.h>
#include <stdint.h>

#define N_NODES 400000
#define N_EDGES 1600000
#define N_GRAPHS 10000
#define SLOPE 0.01f

typedef _Float16 hf4 __attribute__((ext_vector_type(4)));
typedef _Float16 hf8 __attribute__((ext_vector_type(8)));
typedef float f32x4 __attribute__((ext_vector_type(4)));

__device__ __forceinline__ float lrelu(float x) { return x > 0.f ? x : SLOPE * x; }

// ---------------------------------------------------------------------------
// Weight preprocessing (one 64-thread block):
//  WeWi[13][64]  = We @ Wi_bot          bfold = bi + be @ Wi_bot
//  WlT16[l][j][k] = fp16 Wl[l][k][j]
//  WTn[j][d]     = fp16 (Wn @ Wi_top)[d][j]   (d<74; 74..95 zero)   bnWi = bn @ Wi_top
//  WTo[j][d]     = fp16 (Wn @ Wa_top)[d][j] (d<74) | Wa_bot[d-80][j] (80<=d<144) | 0
//  bna           = ba + bn @ Wa_top
__global__ void k_fold(const float* We, const float* be, const float* Wi, const float* bi,
                       const float* Wn, const float* bn, const float* Wa, const float* ba,
                       const float* Wl, float* WeWi, float* bfold, _Float16* WlT16,
                       _Float16* WTn, float* bnWi, _Float16* WTo, float* bna) {
    int j = threadIdx.x;  // 64 threads
    for (int d = 0; d < 13; d++) {
        float acc = 0.f;
        for (int k = 0; k < 64; k++) acc += We[d * 64 + k] * Wi[(64 + k) * 64 + j];
        WeWi[d * 64 + j] = acc;
    }
    float accb = bi[j];
    for (int k = 0; k < 64; k++) accb += be[k] * Wi[(64 + k) * 64 + j];
    bfold[j] = accb;
    for (int l = 0; l < 4; l++)
        for (int k = 0; k < 64; k++)
            WlT16[l * 4096 + j * 64 + k] = (_Float16)Wl[l * 4096 + k * 64 + j];
    for (int d = 0; d < 96; d++) {
        float acc = 0.f;
        if (d < 74)
            for (int k = 0; k < 64; k++) acc += Wn[d * 64 + k] * Wi[k * 64 + j];
        WTn[j * 96 + d] = (_Float16)acc;
    }
    {
        float acc = 0.f;
        for (int k = 0; k < 64; k++) acc += bn[k] * Wi[k * 64 + j];
        bnWi[j] = acc;
    }
    for (int d = 0; d < 160; d++) {
        float acc = 0.f;
        if (d < 74)
            for (int k = 0; k < 64; k++) acc += Wn[d * 64 + k] * Wa[k * 64 + j];
        else if (d >= 80 && d < 144)
            acc = Wa[(64 + d - 80) * 64 + j];
        WTo[j * 160 + d] = (_Float16)acc;
    }
    {
        float acc = ba[j];
        for (int k = 0; k < 64; k++) acc += bn[k] * Wa[k * 64 + j];
        bna[j] = acc;
    }
}

// ---------------------------------------------------------------------------
// nodeWi = nf @ WnWi + bnWi   (MFMA, fp16 out)
__global__ __launch_bounds__(256) void k_node(const float* nf, const _Float16* WTn,
                                              const float* bnWi, _Float16* nodeWi) {
    __shared__ __align__(16) _Float16 A[64 * 104];
    __shared__ __align__(16) _Float16 WT[64 * 104];
    int t = threadIdx.x;
    int n0 = blockIdx.x * 64;
    for (int idx = t; idx < 64 * 96; idx += 256) {
        int r = idx / 96, c = idx % 96;
        float v = (c < 74) ? nf[(size_t)(n0 + r) * 74 + c] : 0.f;
        A[r * 104 + c] = (_Float16)v;
    }
    for (int idx = t; idx < 64 * 24; idx += 256) {
        int r = idx / 24, c4 = idx % 24;
        *(hf4*)&WT[r * 104 + c4 * 4] = *(const hf4*)(WTn + r * 96 + c4 * 4);
    }
    __syncthreads();
    int lane = t & 63, w = t >> 6;
    int m16 = lane & 15, quad = lane >> 4;
    f32x4 acc[4];
#pragma unroll
    for (int jt = 0; jt < 4; jt++) acc[jt] = (f32x4){0.f, 0.f, 0.f, 0.f};
#pragma unroll
    for (int kt = 0; kt < 3; kt++) {
        hf8 a = *(const hf8*)&A[(w * 16 + m16) * 104 + kt * 32 + quad * 8];
#pragma unroll
        for (int jt = 0; jt < 4; jt++) {
            hf8 b = *(const hf8*)&WT[(jt * 16 + m16) * 104 + kt * 32 + quad * 8];
            acc[jt] = __builtin_amdgcn_mfma_f32_16x16x32_f16(a, b, acc[jt], 0, 0, 0);
        }
    }
#pragma unroll
    for (int jt = 0; jt < 4; jt++) {
        int col = jt * 16 + m16;
        float bb = bnWi[col];
#pragma unroll
        for (int r = 0; r < 4; r++) {
            int row = w * 16 + quad * 4 + r;
            nodeWi[(size_t)(n0 + row) * 64 + col] = (_Float16)(acc[jt][r] + bb);
        }
    }
}

// ---------------------------------------------------------------------------
// h = lrelu(nodeWi[src] + ef @ WeWi + bfold); fused scatter: agg[dst] += h
// nodeWi gathers register-prefetched at kernel start (issue-parallel).
__global__ __launch_bounds__(256) void k_h0(const float* ef, const int* src, const int* dst,
                                            const float* WeWi, const float* bfold,
                                            const _Float16* nodeWi, _Float16* h,
                                            __half2* agg2) {
    __shared__ float efL[832];
    __shared__ float WW[832];
    __shared__ float bf[64];
    __shared__ int dstL[64];
    int t = threadIdx.x;
    int e0 = blockIdx.x * 64;
    int j = t & 63, sub = t >> 6;
    int sv[16];
#pragma unroll
    for (int i = 0; i < 16; i++) sv[i] = src[e0 + sub + 4 * i];
    _Float16 nwv[16];
#pragma unroll
    for (int i = 0; i < 16; i++) nwv[i] = nodeWi[(size_t)sv[i] * 64 + j];
    for (int v = t; v < 832; v += 256) efL[v] = ef[(size_t)e0 * 13 + v];
    for (int v = t; v < 832; v += 256) WW[v] = WeWi[v];
    if (t < 64) { bf[t] = bfold[t]; dstL[t] = dst[e0 + t]; }
    __syncthreads();
    float bfj = bf[j];
#pragma unroll
    for (int i = 0; i < 16; i++) {
        int el = sub + 4 * i;
        int e = e0 + el;
        float acc = bfj + (float)nwv[i];
        const float* er = &efL[el * 13];
#pragma unroll
        for (int d = 0; d < 13; d++) acc += er[d] * WW[d * 64 + j];
        float v = lrelu(acc);
        h[(size_t)e * 64 + j] = (_Float16)v;
        float vn = __shfl_down(v, 1, 64);
        if ((j & 1) == 0) {
            __half2 p = __halves2half2(__float2half(v), __float2half(vn));
            unsafeAtomicAdd(&agg2[(size_t)dstL[el] * 32 + (j >> 1)], p);
        }
    }
}

// ---------------------------------------------------------------------------
// h = lrelu(h0 + (agg[src] - h[rev]) @ Wl[l] + bl[l])  IN-PLACE on h, with
// h0 recomputed (nodeWi[src] + ef@WeWi + bfold) and fused scatter into
// aggN[dst] += h_new.  MFMA GEMM, C round-trips through LDS (union region).
// nodeWi gathers register-prefetched in phase A, consumed in phase D —
// latency hidden behind the MFMA + LDS phases.
__global__ __launch_bounds__(256) void k_conv(const _Float16* agg, _Float16* h,
                                              const _Float16* nodeWi, const float* ef,
                                              const int* src, const int* dst,
                                              const float* WeWi, const float* bfold,
                                              const _Float16* WlT16, const float* bl_g,
                                              int layer, __half2* aggN2) {
    __shared__ __align__(16) char uni[18432];
    _Float16* Msh = (_Float16*)uni;           // [64][72] fp16 (phase A/B)
    _Float16* WTs = (_Float16*)(uni + 9216);  // [64][72] fp16 (phase A/B)
    float* Cs = (float*)uni;                  // [64][65] fp32 (phase C/D)
    __shared__ float efL[832];
    __shared__ float WWL[832];
    __shared__ float bfL[64];
    __shared__ int dstL[64];
    int t = threadIdx.x;
    int e0 = blockIdx.x * 64;
    int j = t & 63, sub = t >> 6;
    const _Float16* WTg = WlT16 + layer * 4096;
    // --- phase A: stage WT, M; prefetch nodeWi rows into registers ---
    int sv[16];
#pragma unroll
    for (int i = 0; i < 16; i++) sv[i] = src[e0 + sub + 4 * i];
    _Float16 nwv[16];
#pragma unroll
    for (int i = 0; i < 16; i++) nwv[i] = nodeWi[(size_t)sv[i] * 64 + j];
    for (int i = 0; i < 4; i++) {
        int idx = t + 256 * i;  // 0..1023
        int r = idx >> 4, c4 = idx & 15;
        *(hf4*)&WTs[r * 72 + c4 * 4] = *(const hf4*)(WTg + r * 64 + c4 * 4);
    }
    for (int i = 0; i < 4; i++) {
        int idx = t + 256 * i;
        int e = idx >> 4, k4 = idx & 15;
        int ge = e0 + e;
        int s = src[ge];
        hf4 av = *(const hf4*)(agg + (size_t)s * 64 + k4 * 4);
        hf4 hv = *(const hf4*)(h + (size_t)(ge ^ 1) * 64 + k4 * 4);
        hf4 m;
        m.x = av.x - hv.x; m.y = av.y - hv.y; m.z = av.z - hv.z; m.w = av.w - hv.w;
        *(hf4*)&Msh[e * 72 + k4 * 4] = m;
    }
    for (int v = t; v < 832; v += 256) efL[v] = ef[(size_t)e0 * 13 + v];
    for (int v = t; v < 832; v += 256) WWL[v] = WeWi[v];
    if (t < 64) { bfL[t] = bfold[t]; dstL[t] = dst[e0 + t]; }
    __syncthreads();
    // --- phase B: MFMA ---
    int lane = t & 63, w = t >> 6;
    int m16 = lane & 15, quad = lane >> 4;
    f32x4 acc[4];
#pragma unroll
    for (int jt = 0; jt < 4; jt++) acc[jt] = (f32x4){0.f, 0.f, 0.f, 0.f};
#pragma unroll
    for (int kt = 0; kt < 2; kt++) {
        hf8 a = *(const hf8*)&Msh[(w * 16 + m16) * 72 + kt * 32 + quad * 8];
#pragma unroll
        for (int jt = 0; jt < 4; jt++) {
            hf8 b = *(const hf8*)&WTs[(jt * 16 + m16) * 72 + kt * 32 + quad * 8];
            acc[jt] = __builtin_amdgcn_mfma_f32_16x16x32_f16(a, b, acc[jt], 0, 0, 0);
        }
    }
    __syncthreads();
    // --- phase C: C -> LDS (C layout: col=lane&15, row=quad*4+reg) ---
#pragma unroll
    for (int jt = 0; jt < 4; jt++)
#pragma unroll
        for (int r = 0; r < 4; r++)
            Cs[(w * 16 + quad * 4 + r) * 65 + jt * 16 + m16] = acc[jt][r];
    __syncthreads();
    // --- phase D: epilogue, coalesced column-per-thread + fused scatter ---
    float blj = bl_g[layer * 64 + j];
    float bfj = bfL[j];
#pragma unroll
    for (int i = 0; i < 16; i++) {
        int el = sub + 4 * i;
        int ge = e0 + el;
        float z = bfj + (float)nwv[i];
        const float* er = &efL[el * 13];
#pragma unroll
        for (int d = 0; d < 13; d++) z += er[d] * WWL[d * 64 + j];
        float val = lrelu(lrelu(z) + Cs[el * 65 + j] + blj);
        h[(size_t)ge * 64 + j] = (_Float16)val;
        float vn = __shfl_down(val, 1, 64);
        if ((j & 1) == 0) {
            __half2 p = __halves2half2(__float2half(val), __float2half(vn));
            unsafeAtomicAdd(&aggN2[(size_t)dstL[el] * 32 + (j >> 1)], p);
        }
    }
}

// ---------------------------------------------------------------------------
// z = nf @ Wna + agg @ Wab + bna (MFMA, K=160); g[gid] += lrelu(z)
// Epilogue: round-trip lrelu(z) through LDS, then per-column SEGMENTED
// reduction over the (sorted) gid runs — one coalesced atomic burst per
// gid-run instead of one atomic per node (≈11× fewer atomics; kills the
// same-address L2 atomic serialization that dominated this kernel).
__global__ __launch_bounds__(256) void k_nodeout(const float* nf, const _Float16* agg,
                                                 const _Float16* WTo, const float* bna,
                                                 const int* gidp, float* g) {
    __shared__ __align__(16) char uni[43008];
    _Float16* A = (_Float16*)uni;             // [64][168] fp16 (phase A/B)
    _Float16* WT = (_Float16*)(uni + 21504);  // [64][168] fp16 (phase A/B)
    float* Cs = (float*)uni;                  // [64][66] fp32 (phase C/D overlay)
    __shared__ int gidL[64];
    int t = threadIdx.x;
    int n0 = blockIdx.x * 64;
    for (int idx = t; idx < 64 * 80; idx += 256) {
        int r = idx / 80, c = idx % 80;
        float v = (c < 74) ? nf[(size_t)(n0 + r) * 74 + c] : 0.f;
        A[r * 168 + c] = (_Float16)v;
    }
    for (int idx = t; idx < 64 * 16; idx += 256) {
        int r = idx >> 4, c4 = idx & 15;
        *(hf4*)&A[r * 168 + 80 + c4 * 4] = *(const hf4*)(agg + (size_t)(n0 + r) * 64 + c4 * 4);
    }
    for (int idx = t; idx < 64 * 16; idx += 256) {
        int r = idx >> 4, c = idx & 15;
        A[r * 168 + 144 + c] = (_Float16)0.f;
    }
    for (int idx = t; idx < 64 * 40; idx += 256) {
        int r = idx / 40, c4 = idx % 40;
        *(hf4*)&WT[r * 168 + c4 * 4] = *(const hf4*)(WTo + r * 160 + c4 * 4);
    }
    if (t < 64) gidL[t] = gidp[n0 + t];
    __syncthreads();
    int lane = t & 63, w = t >> 6;
    int m16 = lane & 15, quad = lane >> 4;
    f32x4 acc[4];
#pragma unroll
    for (int jt = 0; jt < 4; jt++) acc[jt] = (f32x4){0.f, 0.f, 0.f, 0.f};
#pragma unroll
    for (int kt = 0; kt < 5; kt++) {
        hf8 a = *(const hf8*)&A[(w * 16 + m16) * 168 + kt * 32 + quad * 8];
#pragma unroll
        for (int jt = 0; jt < 4; jt++) {
            hf8 b = *(const hf8*)&WT[(jt * 16 + m16) * 168 + kt * 32 + quad * 8];
            acc[jt] = __builtin_amdgcn_mfma_f32_16x16x32_f16(a, b, acc[jt], 0, 0, 0);
        }
    }
    __syncthreads();  // everyone done reading A/WT before Cs overlay
    // --- phase C: lrelu(z) -> LDS (stride 66: 2-way banks both directions) ---
#pragma unroll
    for (int jt = 0; jt < 4; jt++) {
        int col = jt * 16 + m16;
        float bb = bna[col];
#pragma unroll
        for (int r = 0; r < 4; r++) {
            int row = w * 16 + quad * 4 + r;
            Cs[row * 66 + col] = lrelu(acc[jt][r] + bb);
        }
    }
    __syncthreads();
    // --- phase D: segmented flush. Wave w owns rows [w*16, w*16+16), lane j
    // owns column j. gid is sorted so runs are contiguous; the run-break test
    // is wave-uniform (all lanes share the row sequence) -> no divergence,
    // and each flush is a 64-lane coalesced atomic burst. ---
    int jj = t & 63, sub = t >> 6;
    int r0 = sub * 16;
    float run = Cs[r0 * 66 + jj];
    int curg = gidL[r0];
#pragma unroll
    for (int r = r0 + 1; r < r0 + 16; r++) {
        int gg = gidL[r];
        float v = Cs[r * 66 + jj];
        if (gg == curg) {
            run += v;
        } else {
            atomicAdd(&g[(size_t)curg * 64 + jj], run);
            curg = gg;
            run = v;
        }
    }
    atomicAdd(&g[(size_t)curg * 64 + jj], run);
}

// ---------------------------------------------------------------------------
// out = lrelu(g @ W1 + b1) @ W2 + b2   (one wave per graph)
__global__ __launch_bounds__(256) void k_head(const float* g, const float* W1,
                                              const float* b1, const float* W2,
                                              const float* b2, float* out) {
    __shared__ float W1L[4096];
    int t = threadIdx.x;
    for (int v = t; v < 4096; v += 256) W1L[v] = W1[v];
    __syncthreads();
    int w = t >> 6, j = t & 63;
    int graph = blockIdx.x * 4 + w;
    if (graph >= N_GRAPHS) return;
    const float* gr = g + (size_t)graph * 64;
    float acc = b1[j];
    for (int k = 0; k < 64; k++) acc += gr[k] * W1L[k * 64 + j];
    float p = lrelu(acc) * W2[j];
    for (int off = 32; off > 0; off >>= 1) p += __shfl_down(p, off, 64);
    if (j == 0) out[graph] = p + b2[0];
}

// ---------------------------------------------------------------------------
extern "C" void kernel_launch(void* const* d_in, const int* in_sizes, int n_in,
                              void* d_out, int out_size, void* d_ws, size_t ws_size,
                              hipStream_t stream) {
    const float* nf = (const float*)d_in[0];
    const float* ef = (const float*)d_in[1];
    const int* src = (const int*)d_in[2];
    const int* dst = (const int*)d_in[3];
    const int* gid = (const int*)d_in[4];
    const float* Wn = (const float*)d_in[5];
    const float* bn = (const float*)d_in[6];
    const float* We = (const float*)d_in[7];
    const float* be = (const float*)d_in[8];
    const float* Wi = (const float*)d_in[9];
    const float* bi = (const float*)d_in[10];
    const float* Wa = (const float*)d_in[11];
    const float* ba = (const float*)d_in[12];
    const float* Wl = (const float*)d_in[13];
    const float* bl = (const float*)d_in[14];
    const float* W1 = (const float*)d_in[15];
    const float* b1 = (const float*)d_in[16];
    const float* W2 = (const float*)d_in[17];
    const float* b2 = (const float*)d_in[18];

    char* ws = (char*)d_ws;
    size_t off = 0;
    auto alloc = [&](size_t bytes) -> char* {
        char* p = ws + off;
        off += (bytes + 255) & ~(size_t)255;
        return p;
    };
    // total ~344 MiB
    float* WeWi = (float*)alloc(13 * 64 * 4);
    float* bfold = (float*)alloc(64 * 4);
    _Float16* WlT16 = (_Float16*)alloc(4 * 4096 * 2);
    _Float16* WTn = (_Float16*)alloc(64 * 96 * 2);
    float* bnWi = (float*)alloc(64 * 4);
    _Float16* WTo = (_Float16*)alloc(64 * 160 * 2);
    float* bna = (float*)alloc(64 * 4);
    _Float16* nodeWi = (_Float16*)alloc((size_t)N_NODES * 64 * 2);
    _Float16* h = (_Float16*)alloc((size_t)N_EDGES * 64 * 2);
    _Float16* aggA = (_Float16*)alloc((size_t)N_NODES * 64 * 2);
    _Float16* aggB = (_Float16*)alloc((size_t)N_NODES * 64 * 2);
    float* g = (float*)alloc((size_t)N_GRAPHS * 64 * 4);

    hipLaunchKernelGGL(k_fold, dim3(1), dim3(64), 0, stream, We, be, Wi, bi, Wn, bn, Wa, ba,
                       Wl, WeWi, bfold, WlT16, WTn, bnWi, WTo, bna);
    hipLaunchKernelGGL(k_node, dim3(N_NODES / 64), dim3(256), 0, stream, nf, WTn, bnWi, nodeWi);
    hipMemsetAsync(aggA, 0, (size_t)N_NODES * 64 * 2, stream);
    hipLaunchKernelGGL(k_h0, dim3(N_EDGES / 64), dim3(256), 0, stream, ef, src, dst, WeWi,
                       bfold, nodeWi, h, (__half2*)aggA);

    _Float16* cur = aggA;
    _Float16* nxt = aggB;
    for (int l = 0; l < 4; l++) {
        hipMemsetAsync(nxt, 0, (size_t)N_NODES * 64 * 2, stream);
        hipLaunchKernelGGL(k_conv, dim3(N_EDGES / 64), dim3(256), 0, stream, cur, h, nodeWi,
                           ef, src, dst, WeWi, bfold, WlT16, bl, l, (__half2*)nxt);
        _Float16* tmp = cur; cur = nxt; nxt = tmp;
    }
    hipMemsetAsync(g, 0, (size_t)N_GRAPHS * 64 * 4, stream);
    hipLaunchKernelGGL(k_nodeout, dim3(N_NODES / 64), dim3(256), 0, stream, nf, cur, WTo, bna,
                       gid, g);
    hipLaunchKernelGGL(k_head, dim3(N_GRAPHS / 4), dim3(256), 0, stream, g, W1, b1, W2, b2,
                       (float*)d_out);
}

// Round 3
// 2249.125 us; speedup vs baseline: 1.0734x; 1.0030x over previous
//
#include <hip/hip_runtime.h>
#include <hip/hip_fp16.h>
#include <stdint.h>

#define N_NODES 400000
#define N_EDGES 1600000
#define N_GRAPHS 10000
#define SLOPE 0.01f

typedef _Float16 hf4 __attribute__((ext_vector_type(4)));
typedef _Float16 hf8 __attribute__((ext_vector_type(8)));
typedef float f32x4 __attribute__((ext_vector_type(4)));

__device__ __forceinline__ float lrelu(float x) { return x > 0.f ? x : SLOPE * x; }

// ---------------------------------------------------------------------------
// Weight preprocessing (one 64-thread block):
//  WeWi[13][64]  = We @ Wi_bot          bfold = bi + be @ Wi_bot
//  WlT16[l][j][k] = fp16 Wl[l][k][j]
//  WTn[j][d]     = fp16 (Wn @ Wi_top)[d][j]   (d<74; 74..95 zero)   bnWi = bn @ Wi_top
//  WTo[j][d]     = fp16 (Wn @ Wa_top)[d][j] (d<74) | Wa_bot[d-80][j] (80<=d<144) | 0
//  bna           = ba + bn @ Wa_top
__global__ void k_fold(const float* We, const float* be, const float* Wi, const float* bi,
                       const float* Wn, const float* bn, const float* Wa, const float* ba,
                       const float* Wl, float* WeWi, float* bfold, _Float16* WlT16,
                       _Float16* WTn, float* bnWi, _Float16* WTo, float* bna) {
    int j = threadIdx.x;  // 64 threads
    for (int d = 0; d < 13; d++) {
        float acc = 0.f;
        for (int k = 0; k < 64; k++) acc += We[d * 64 + k] * Wi[(64 + k) * 64 + j];
        WeWi[d * 64 + j] = acc;
    }
    float accb = bi[j];
    for (int k = 0; k < 64; k++) accb += be[k] * Wi[(64 + k) * 64 + j];
    bfold[j] = accb;
    for (int l = 0; l < 4; l++)
        for (int k = 0; k < 64; k++)
            WlT16[l * 4096 + j * 64 + k] = (_Float16)Wl[l * 4096 + k * 64 + j];
    for (int d = 0; d < 96; d++) {
        float acc = 0.f;
        if (d < 74)
            for (int k = 0; k < 64; k++) acc += Wn[d * 64 + k] * Wi[k * 64 + j];
        WTn[j * 96 + d] = (_Float16)acc;
    }
    {
        float acc = 0.f;
        for (int k = 0; k < 64; k++) acc += bn[k] * Wi[k * 64 + j];
        bnWi[j] = acc;
    }
    for (int d = 0; d < 160; d++) {
        float acc = 0.f;
        if (d < 74)
            for (int k = 0; k < 64; k++) acc += Wn[d * 64 + k] * Wa[k * 64 + j];
        else if (d >= 80 && d < 144)
            acc = Wa[(64 + d - 80) * 64 + j];
        WTo[j * 160 + d] = (_Float16)acc;
    }
    {
        float acc = ba[j];
        for (int k = 0; k < 64; k++) acc += bn[k] * Wa[k * 64 + j];
        bna[j] = acc;
    }
}

// ---------------------------------------------------------------------------
// nodeWi = nf @ WnWi + bnWi   (MFMA, fp16 out)
__global__ __launch_bounds__(256) void k_node(const float* nf, const _Float16* WTn,
                                              const float* bnWi, _Float16* nodeWi) {
    __shared__ __align__(16) _Float16 A[64 * 104];
    __shared__ __align__(16) _Float16 WT[64 * 104];
    int t = threadIdx.x;
    int n0 = blockIdx.x * 64;
    for (int idx = t; idx < 64 * 96; idx += 256) {
        int r = idx / 96, c = idx % 96;
        float v = (c < 74) ? nf[(size_t)(n0 + r) * 74 + c] : 0.f;
        A[r * 104 + c] = (_Float16)v;
    }
    for (int idx = t; idx < 64 * 24; idx += 256) {
        int r = idx / 24, c4 = idx % 24;
        *(hf4*)&WT[r * 104 + c4 * 4] = *(const hf4*)(WTn + r * 96 + c4 * 4);
    }
    __syncthreads();
    int lane = t & 63, w = t >> 6;
    int m16 = lane & 15, quad = lane >> 4;
    f32x4 acc[4];
#pragma unroll
    for (int jt = 0; jt < 4; jt++) acc[jt] = (f32x4){0.f, 0.f, 0.f, 0.f};
#pragma unroll
    for (int kt = 0; kt < 3; kt++) {
        hf8 a = *(const hf8*)&A[(w * 16 + m16) * 104 + kt * 32 + quad * 8];
#pragma unroll
        for (int jt = 0; jt < 4; jt++) {
            hf8 b = *(const hf8*)&WT[(jt * 16 + m16) * 104 + kt * 32 + quad * 8];
            acc[jt] = __builtin_amdgcn_mfma_f32_16x16x32_f16(a, b, acc[jt], 0, 0, 0);
        }
    }
#pragma unroll
    for (int jt = 0; jt < 4; jt++) {
        int col = jt * 16 + m16;
        float bb = bnWi[col];
#pragma unroll
        for (int r = 0; r < 4; r++) {
            int row = w * 16 + quad * 4 + r;
            nodeWi[(size_t)(n0 + row) * 64 + col] = (_Float16)(acc[jt][r] + bb);
        }
    }
}

// ---------------------------------------------------------------------------
// h0 = lrelu(nodeWi[src] + ef @ WeWi + bfold); fused scatter: agg[dst] += h0
__global__ __launch_bounds__(256) void k_h0(const float* ef, const int* src, const int* dst,
                                            const float* WeWi, const float* bfold,
                                            const _Float16* nodeWi, _Float16* h0,
                                            __half2* agg2) {
    __shared__ float efL[832];
    __shared__ float WW[832];
    __shared__ float bf[64];
    __shared__ int dstL[64];
    int t = threadIdx.x;
    int e0 = blockIdx.x * 64;
    int j = t & 63, sub = t >> 6;
    int sv[16];
#pragma unroll
    for (int i = 0; i < 16; i++) sv[i] = src[e0 + sub + 4 * i];
    _Float16 nwv[16];
#pragma unroll
    for (int i = 0; i < 16; i++) nwv[i] = nodeWi[(size_t)sv[i] * 64 + j];
    for (int v = t; v < 832; v += 256) efL[v] = ef[(size_t)e0 * 13 + v];
    for (int v = t; v < 832; v += 256) WW[v] = WeWi[v];
    if (t < 64) { bf[t] = bfold[t]; dstL[t] = dst[e0 + t]; }
    __syncthreads();
    float bfj = bf[j];
#pragma unroll
    for (int i = 0; i < 16; i++) {
        int el = sub + 4 * i;
        int e = e0 + el;
        float acc = bfj + (float)nwv[i];
        const float* er = &efL[el * 13];
#pragma unroll
        for (int d = 0; d < 13; d++) acc += er[d] * WW[d * 64 + j];
        float v = lrelu(acc);
        h0[(size_t)e * 64 + j] = (_Float16)v;
        float vn = __shfl_down(v, 1, 64);
        if ((j & 1) == 0) {
            __half2 p = __halves2half2(__float2half(v), __float2half(vn));
            unsafeAtomicAdd(&agg2[(size_t)dstL[el] * 32 + (j >> 1)], p);
        }
    }
}

// ---------------------------------------------------------------------------
// PATH A conv: h_out = lrelu(h0 + (agg[src] - h_in[rev]) @ Wl + bl), h0 READ.
// Kills the 13-FMA/edge recompute + ef/WeWi staging + nodeWi gathers that
// made this kernel VALU-bound (50% VALUBusy at 29% HBM).
__global__ __launch_bounds__(256) void k_conv_h0(const _Float16* agg, const _Float16* h_in,
                                                 _Float16* h_out, const _Float16* h0,
                                                 const int* src, const int* dst,
                                                 const _Float16* WlT16, const float* bl_g,
                                                 int layer, __half2* aggN2) {
    __shared__ __align__(16) char uni[18432];
    _Float16* Msh = (_Float16*)uni;           // [64][72] fp16 (phase A/B)
    _Float16* WTs = (_Float16*)(uni + 9216);  // [64][72] fp16 (phase A/B)
    float* Cs = (float*)uni;                  // [64][65] fp32 (phase C/D)
    __shared__ int dstL[64];
    int t = threadIdx.x;
    int e0 = blockIdx.x * 64;
    int j = t & 63, sub = t >> 6;
    const _Float16* WTg = WlT16 + layer * 4096;
    // --- phase A: prefetch h0 rows (coalesced) into regs; stage WT, M ---
    _Float16 h0v[16];
#pragma unroll
    for (int i = 0; i < 16; i++) h0v[i] = h0[(size_t)(e0 + sub + 4 * i) * 64 + j];
    for (int i = 0; i < 4; i++) {
        int idx = t + 256 * i;  // 0..1023
        int r = idx >> 4, c4 = idx & 15;
        *(hf4*)&WTs[r * 72 + c4 * 4] = *(const hf4*)(WTg + r * 64 + c4 * 4);
    }
    for (int i = 0; i < 4; i++) {
        int idx = t + 256 * i;
        int e = idx >> 4, k4 = idx & 15;
        int ge = e0 + e;
        int s = src[ge];
        hf4 av = *(const hf4*)(agg + (size_t)s * 64 + k4 * 4);
        hf4 hv = *(const hf4*)(h_in + (size_t)(ge ^ 1) * 64 + k4 * 4);
        hf4 m;
        m.x = av.x - hv.x; m.y = av.y - hv.y; m.z = av.z - hv.z; m.w = av.w - hv.w;
        *(hf4*)&Msh[e * 72 + k4 * 4] = m;
    }
    if (t < 64) dstL[t] = dst[e0 + t];
    __syncthreads();
    // --- phase B: MFMA ---
    int lane = t & 63, w = t >> 6;
    int m16 = lane & 15, quad = lane >> 4;
    f32x4 acc[4];
#pragma unroll
    for (int jt = 0; jt < 4; jt++) acc[jt] = (f32x4){0.f, 0.f, 0.f, 0.f};
#pragma unroll
    for (int kt = 0; kt < 2; kt++) {
        hf8 a = *(const hf8*)&Msh[(w * 16 + m16) * 72 + kt * 32 + quad * 8];
#pragma unroll
        for (int jt = 0; jt < 4; jt++) {
            hf8 b = *(const hf8*)&WTs[(jt * 16 + m16) * 72 + kt * 32 + quad * 8];
            acc[jt] = __builtin_amdgcn_mfma_f32_16x16x32_f16(a, b, acc[jt], 0, 0, 0);
        }
    }
    __syncthreads();
    // --- phase C: C -> LDS ---
#pragma unroll
    for (int jt = 0; jt < 4; jt++)
#pragma unroll
        for (int r = 0; r < 4; r++)
            Cs[(w * 16 + quad * 4 + r) * 65 + jt * 16 + m16] = acc[jt][r];
    __syncthreads();
    // --- phase D: epilogue + fused scatter ---
    float blj = bl_g[layer * 64 + j];
#pragma unroll
    for (int i = 0; i < 16; i++) {
        int el = sub + 4 * i;
        int ge = e0 + el;
        float val = lrelu((float)h0v[i] + Cs[el * 65 + j] + blj);
        h_out[(size_t)ge * 64 + j] = (_Float16)val;
        float vn = __shfl_down(val, 1, 64);
        if ((j & 1) == 0) {
            __half2 p = __halves2half2(__float2half(val), __float2half(vn));
            unsafeAtomicAdd(&aggN2[(size_t)dstL[el] * 32 + (j >> 1)], p);
        }
    }
}

// ---------------------------------------------------------------------------
// PATH B conv (fallback, = round-1 verified): h0 recomputed in epilogue.
__global__ __launch_bounds__(256) void k_conv_rc(const _Float16* agg, _Float16* h,
                                                 const _Float16* nodeWi, const float* ef,
                                                 const int* src, const int* dst,
                                                 const float* WeWi, const float* bfold,
                                                 const _Float16* WlT16, const float* bl_g,
                                                 int layer, __half2* aggN2) {
    __shared__ __align__(16) char uni[18432];
    _Float16* Msh = (_Float16*)uni;
    _Float16* WTs = (_Float16*)(uni + 9216);
    float* Cs = (float*)uni;
    __shared__ float efL[832];
    __shared__ float WWL[832];
    __shared__ float bfL[64];
    __shared__ int dstL[64];
    int t = threadIdx.x;
    int e0 = blockIdx.x * 64;
    int j = t & 63, sub = t >> 6;
    const _Float16* WTg = WlT16 + layer * 4096;
    int sv[16];
#pragma unroll
    for (int i = 0; i < 16; i++) sv[i] = src[e0 + sub + 4 * i];
    _Float16 nwv[16];
#pragma unroll
    for (int i = 0; i < 16; i++) nwv[i] = nodeWi[(size_t)sv[i] * 64 + j];
    for (int i = 0; i < 4; i++) {
        int idx = t + 256 * i;
        int r = idx >> 4, c4 = idx & 15;
        *(hf4*)&WTs[r * 72 + c4 * 4] = *(const hf4*)(WTg + r * 64 + c4 * 4);
    }
    for (int i = 0; i < 4; i++) {
        int idx = t + 256 * i;
        int e = idx >> 4, k4 = idx & 15;
        int ge = e0 + e;
        int s = src[ge];
        hf4 av = *(const hf4*)(agg + (size_t)s * 64 + k4 * 4);
        hf4 hv = *(const hf4*)(h + (size_t)(ge ^ 1) * 64 + k4 * 4);
        hf4 m;
        m.x = av.x - hv.x; m.y = av.y - hv.y; m.z = av.z - hv.z; m.w = av.w - hv.w;
        *(hf4*)&Msh[e * 72 + k4 * 4] = m;
    }
    for (int v = t; v < 832; v += 256) efL[v] = ef[(size_t)e0 * 13 + v];
    for (int v = t; v < 832; v += 256) WWL[v] = WeWi[v];
    if (t < 64) { bfL[t] = bfold[t]; dstL[t] = dst[e0 + t]; }
    __syncthreads();
    int lane = t & 63, w = t >> 6;
    int m16 = lane & 15, quad = lane >> 4;
    f32x4 acc[4];
#pragma unroll
    for (int jt = 0; jt < 4; jt++) acc[jt] = (f32x4){0.f, 0.f, 0.f, 0.f};
#pragma unroll
    for (int kt = 0; kt < 2; kt++) {
        hf8 a = *(const hf8*)&Msh[(w * 16 + m16) * 72 + kt * 32 + quad * 8];
#pragma unroll
        for (int jt = 0; jt < 4; jt++) {
            hf8 b = *(const hf8*)&WTs[(jt * 16 + m16) * 72 + kt * 32 + quad * 8];
            acc[jt] = __builtin_amdgcn_mfma_f32_16x16x32_f16(a, b, acc[jt], 0, 0, 0);
        }
    }
    __syncthreads();
#pragma unroll
    for (int jt = 0; jt < 4; jt++)
#pragma unroll
        for (int r = 0; r < 4; r++)
            Cs[(w * 16 + quad * 4 + r) * 65 + jt * 16 + m16] = acc[jt][r];
    __syncthreads();
    float blj = bl_g[layer * 64 + j];
    float bfj = bfL[j];
#pragma unroll
    for (int i = 0; i < 16; i++) {
        int el = sub + 4 * i;
        int ge = e0 + el;
        float z = bfj + (float)nwv[i];
        const float* er = &efL[el * 13];
#pragma unroll
        for (int d = 0; d < 13; d++) z += er[d] * WWL[d * 64 + j];
        float val = lrelu(lrelu(z) + Cs[el * 65 + j] + blj);
        h[(size_t)ge * 64 + j] = (_Float16)val;
        float vn = __shfl_down(val, 1, 64);
        if ((j & 1) == 0) {
            __half2 p = __halves2half2(__float2half(val), __float2half(vn));
            unsafeAtomicAdd(&aggN2[(size_t)dstL[el] * 32 + (j >> 1)], p);
        }
    }
}

// ---------------------------------------------------------------------------
// z = nf @ Wna + agg @ Wab + bna (MFMA, K=160); g[gid] += lrelu(z)
// Segmented flush over sorted gid runs (one atomic burst per run).
__global__ __launch_bounds__(256) void k_nodeout(const float* nf, const _Float16* agg,
                                                 const _Float16* WTo, const float* bna,
                                                 const int* gidp, float* g) {
    __shared__ __align__(16) char uni[43008];
    _Float16* A = (_Float16*)uni;             // [64][168] fp16 (phase A/B)
    _Float16* WT = (_Float16*)(uni + 21504);  // [64][168] fp16 (phase A/B)
    float* Cs = (float*)uni;                  // [64][66] fp32 (phase C/D overlay)
    __shared__ int gidL[64];
    int t = threadIdx.x;
    int n0 = blockIdx.x * 64;
    for (int idx = t; idx < 64 * 80; idx += 256) {
        int r = idx / 80, c = idx % 80;
        float v = (c < 74) ? nf[(size_t)(n0 + r) * 74 + c] : 0.f;
        A[r * 168 + c] = (_Float16)v;
    }
    for (int idx = t; idx < 64 * 16; idx += 256) {
        int r = idx >> 4, c4 = idx & 15;
        *(hf4*)&A[r * 168 + 80 + c4 * 4] = *(const hf4*)(agg + (size_t)(n0 + r) * 64 + c4 * 4);
    }
    for (int idx = t; idx < 64 * 16; idx += 256) {
        int r = idx >> 4, c = idx & 15;
        A[r * 168 + 144 + c] = (_Float16)0.f;
    }
    for (int idx = t; idx < 64 * 40; idx += 256) {
        int r = idx / 40, c4 = idx % 40;
        *(hf4*)&WT[r * 168 + c4 * 4] = *(const hf4*)(WTo + r * 160 + c4 * 4);
    }
    if (t < 64) gidL[t] = gidp[n0 + t];
    __syncthreads();
    int lane = t & 63, w = t >> 6;
    int m16 = lane & 15, quad = lane >> 4;
    f32x4 acc[4];
#pragma unroll
    for (int jt = 0; jt < 4; jt++) acc[jt] = (f32x4){0.f, 0.f, 0.f, 0.f};
#pragma unroll
    for (int kt = 0; kt < 5; kt++) {
        hf8 a = *(const hf8*)&A[(w * 16 + m16) * 168 + kt * 32 + quad * 8];
#pragma unroll
        for (int jt = 0; jt < 4; jt++) {
            hf8 b = *(const hf8*)&WT[(jt * 16 + m16) * 168 + kt * 32 + quad * 8];
            acc[jt] = __builtin_amdgcn_mfma_f32_16x16x32_f16(a, b, acc[jt], 0, 0, 0);
        }
    }
    __syncthreads();
#pragma unroll
    for (int jt = 0; jt < 4; jt++) {
        int col = jt * 16 + m16;
        float bb = bna[col];
#pragma unroll
        for (int r = 0; r < 4; r++) {
            int row = w * 16 + quad * 4 + r;
            Cs[row * 66 + col] = lrelu(acc[jt][r] + bb);
        }
    }
    __syncthreads();
    int jj = t & 63, sub = t >> 6;
    int r0 = sub * 16;
    float run = Cs[r0 * 66 + jj];
    int curg = gidL[r0];
#pragma unroll
    for (int r = r0 + 1; r < r0 + 16; r++) {
        int gg = gidL[r];
        float v = Cs[r * 66 + jj];
        if (gg == curg) {
            run += v;
        } else {
            atomicAdd(&g[(size_t)curg * 64 + jj], run);
            curg = gg;
            run = v;
        }
    }
    atomicAdd(&g[(size_t)curg * 64 + jj], run);
}

// ---------------------------------------------------------------------------
// out = lrelu(g @ W1 + b1) @ W2 + b2   (one wave per graph)
__global__ __launch_bounds__(256) void k_head(const float* g, const float* W1,
                                              const float* b1, const float* W2,
                                              const float* b2, float* out) {
    __shared__ float W1L[4096];
    int t = threadIdx.x;
    for (int v = t; v < 4096; v += 256) W1L[v] = W1[v];
    __syncthreads();
    int w = t >> 6, j = t & 63;
    int graph = blockIdx.x * 4 + w;
    if (graph >= N_GRAPHS) return;
    const float* gr = g + (size_t)graph * 64;
    float acc = b1[j];
    for (int k = 0; k < 64; k++) acc += gr[k] * W1L[k * 64 + j];
    float p = lrelu(acc) * W2[j];
    for (int off = 32; off > 0; off >>= 1) p += __shfl_down(p, off, 64);
    if (j == 0) out[graph] = p + b2[0];
}

// ---------------------------------------------------------------------------
extern "C" void kernel_launch(void* const* d_in, const int* in_sizes, int n_in,
                              void* d_out, int out_size, void* d_ws, size_t ws_size,
                              hipStream_t stream) {
    const float* nf = (const float*)d_in[0];
    const float* ef = (const float*)d_in[1];
    const int* src = (const int*)d_in[2];
    const int* dst = (const int*)d_in[3];
    const int* gid = (const int*)d_in[4];
    const float* Wn = (const float*)d_in[5];
    const float* bn = (const float*)d_in[6];
    const float* We = (const float*)d_in[7];
    const float* be = (const float*)d_in[8];
    const float* Wi = (const float*)d_in[9];
    const float* bi = (const float*)d_in[10];
    const float* Wa = (const float*)d_in[11];
    const float* ba = (const float*)d_in[12];
    const float* Wl = (const float*)d_in[13];
    const float* bl = (const float*)d_in[14];
    const float* W1 = (const float*)d_in[15];
    const float* b1 = (const float*)d_in[16];
    const float* W2 = (const float*)d_in[17];
    const float* b2 = (const float*)d_in[18];

    char* ws = (char*)d_ws;
    size_t off = 0;
    auto alloc = [&](size_t bytes) -> char* {
        char* p = ws + off;
        off += (bytes + 255) & ~(size_t)255;
        return p;
    };
    // common small weights (~70 KB)
    float* WeWi = (float*)alloc(13 * 64 * 4);
    float* bfold = (float*)alloc(64 * 4);
    _Float16* WlT16 = (_Float16*)alloc(4 * 4096 * 2);
    _Float16* WTn = (_Float16*)alloc(64 * 96 * 2);
    float* bnWi = (float*)alloc(64 * 4);
    _Float16* WTo = (_Float16*)alloc(64 * 160 * 2);
    float* bna = (float*)alloc(64 * 4);

    const size_t HBYTES = (size_t)N_EDGES * 64 * 2;   // 204.8 MB
    const size_t ABYTES = (size_t)N_NODES * 64 * 2;   // 51.2 MB
    // Path A needs: weights + h0 + aggA + aggB + g + X(h/nodeWi alias) ≈ 514.7 MB
    bool bigws = ws_size >= (size_t)516 * 1000 * 1000;

    hipLaunchKernelGGL(k_fold, dim3(1), dim3(64), 0, stream, We, be, Wi, bi, Wn, bn, Wa, ba,
                       Wl, WeWi, bfold, WlT16, WTn, bnWi, WTo, bna);

    if (bigws) {
        // --- PATH A: materialized h0; nodeWi aliases the h buffer (dead after k_h0) ---
        _Float16* h0 = (_Float16*)alloc(HBYTES);
        _Float16* aggA = (_Float16*)alloc(ABYTES);
        _Float16* aggB = (_Float16*)alloc(ABYTES);
        float* g = (float*)alloc((size_t)N_GRAPHS * 64 * 4);
        _Float16* h = (_Float16*)alloc(HBYTES);  // alias region: nodeWi lives here first
        _Float16* nodeWi = h;                    // 51.2 MB prefix, dead after k_h0

        hipLaunchKernelGGL(k_node, dim3(N_NODES / 64), dim3(256), 0, stream, nf, WTn, bnWi,
                           nodeWi);
        hipMemsetAsync(aggA, 0, ABYTES, stream);
        hipLaunchKernelGGL(k_h0, dim3(N_EDGES / 64), dim3(256), 0, stream, ef, src, dst, WeWi,
                           bfold, nodeWi, h0, (__half2*)aggA);

        _Float16* cur = aggA;
        _Float16* nxt = aggB;
        for (int l = 0; l < 4; l++) {
            hipMemsetAsync(nxt, 0, ABYTES, stream);
            hipLaunchKernelGGL(k_conv_h0, dim3(N_EDGES / 64), dim3(256), 0, stream, cur,
                               (l == 0) ? h0 : h, h, h0, src, dst, WlT16, bl, l,
                               (__half2*)nxt);
            _Float16* tmp = cur; cur = nxt; nxt = tmp;
        }
        hipMemsetAsync(g, 0, (size_t)N_GRAPHS * 64 * 4, stream);
        hipLaunchKernelGGL(k_nodeout, dim3(N_NODES / 64), dim3(256), 0, stream, nf, cur, WTo,
                           bna, gid, g);
        hipLaunchKernelGGL(k_head, dim3(N_GRAPHS / 4), dim3(256), 0, stream, g, W1, b1, W2, b2,
                           (float*)d_out);
    } else {
        // --- PATH B: round-1 verified fallback (h0 recomputed per layer) ~361 MB ---
        _Float16* nodeWi = (_Float16*)alloc(ABYTES);
        _Float16* h = (_Float16*)alloc(HBYTES);
        _Float16* aggA = (_Float16*)alloc(ABYTES);
        _Float16* aggB = (_Float16*)alloc(ABYTES);
        float* g = (float*)alloc((size_t)N_GRAPHS * 64 * 4);

        hipLaunchKernelGGL(k_node, dim3(N_NODES / 64), dim3(256), 0, stream, nf, WTn, bnWi,
                           nodeWi);
        hipMemsetAsync(aggA, 0, ABYTES, stream);
        hipLaunchKernelGGL(k_h0, dim3(N_EDGES / 64), dim3(256), 0, stream, ef, src, dst, WeWi,
                           bfold, nodeWi, h, (__half2*)aggA);

        _Float16* cur = aggA;
        _Float16* nxt = aggB;
        for (int l = 0; l < 4; l++) {
            hipMemsetAsync(nxt, 0, ABYTES, stream);
            hipLaunchKernelGGL(k_conv_rc, dim3(N_EDGES / 64), dim3(256), 0, stream, cur, h,
                               nodeWi, ef, src, dst, WeWi, bfold, WlT16, bl, l,
                               (__half2*)nxt);
            _Float16* tmp = cur; cur = nxt; nxt = tmp;
        }
        hipMemsetAsync(g, 0, (size_t)N_GRAPHS * 64 * 4, stream);
        hipLaunchKernelGGL(k_nodeout, dim3(N_NODES / 64), dim3(256), 0, stream, nf, cur, WTo,
                           bna, gid, g);
        hipLaunchKernelGGL(k_head, dim3(N_GRAPHS / 4), dim3(256), 0, stream, g, W1, b1, W2, b2,
                           (float*)d_out);
    }
}